// Round 8
// baseline (145.988 us; speedup 1.0000x reference)
//
#include <hip/hip_runtime.h>
#include <math.h>

#define NB 4
#define LL 4096
#define DD 1024
#define MM 256

typedef short s16x8 __attribute__((ext_vector_type(8)));
typedef short s16x4 __attribute__((ext_vector_type(4)));
typedef float fx4 __attribute__((ext_vector_type(4)));
typedef unsigned u32x2 __attribute__((ext_vector_type(2)));
typedef unsigned u32x4 __attribute__((ext_vector_type(4)));

__device__ __forceinline__ float b2f(short s) {
  union { unsigned u; float f; } v;
  v.u = ((unsigned)(unsigned short)s) << 16;
  return v.f;
}
__device__ __forceinline__ short f2b(float f) {
  union { float f; unsigned u; } v;
  v.f = f;
  unsigned r = (v.u + 0x7fffu + ((v.u >> 16) & 1u)) >> 16;
  return (short)(unsigned short)r;
}
// packed fp32->bf16 (RNE), 2 values per instruction
__device__ __forceinline__ unsigned cvt2(float lo, float hi) {
  unsigned r;
  asm("v_cvt_pk_bf16_f32 %0, %1, %2" : "=v"(r) : "v"(lo), "v"(hi));
  return r;
}
// 4-chunk swizzle key for 32-k-wide GLL16 tiles
__device__ __forceinline__ int keyf(int m) { return (m ^ (m >> 2)) & 3; }

typedef __attribute__((address_space(1))) const void* gas1_t;
typedef __attribute__((address_space(3))) void* las3_t;
#define GLL16(g, l) __builtin_amdgcn_global_load_lds((gas1_t)(const void*)(g), (las3_t)(void*)(l), 16, 0, 0)

// ---------------- cast fp32 -> bf16 (P only) ----------------
__global__ __launch_bounds__(256) void k_cast(const float* __restrict__ in, short* __restrict__ out, int n4) {
  int i = blockIdx.x * 256 + threadIdx.x;
  if (i >= n4) return;
  float4 v = ((const float4*)in)[i];
  s16x4 s;
  s[0] = f2b(v.x); s[1] = f2b(v.y); s[2] = f2b(v.z); s[3] = f2b(v.w);
  ((s16x4*)out)[i] = s;
}

// ---------------- rf GEMM: 64l x 256m, outer KC=256 (16 float4/thread in flight), inner BK=32 ----------------
// z<4: rf_q (B,L,M) incl 1/sqrt(M); z>=4: rf_kT (B,M,L) + Z atomics.
__global__ __launch_bounds__(256, 2) void k_qk(const float* __restrict__ Q, const float* __restrict__ K,
                                               const short* __restrict__ Pb,
                                               short* __restrict__ rfq, short* __restrict__ rfkT,
                                               float* __restrict__ Zz) {
  __shared__ short As[64 * 256];   // 32 KB: [64 l][256 k], 16B-granule XOR swizzle by row&7
  __shared__ short Bs[2][8192];    // 2 x 16 KB: [256 m][32 k], keyf chunk swizzle
  int z = blockIdx.z, mode = z >> 2, b = z & 3;
  int l0 = blockIdx.x * 64;
  const float* X = mode ? K : Q;
  int tid = threadIdx.x, lane = tid & 63, w = tid >> 6;   // wave grid 1(l) x 4(m)
  int m16 = lane & 15, kg = lane >> 4;

  // A staging: row = tid>>2 (64 rows), 64 contiguous k (256 B) per thread
  int arow = tid >> 2, acol = (tid & 3) * 64;
  int akey = (arow & 7) << 4;                     // byte-granule-16 XOR key
  char* Asb = (char*)As + arow * 512;

  fx4 acc[4][4] = {};

  for (int c = 0; c < 4; ++c) {
    if (c) __syncthreads();                       // all waves done with previous A chunk + Bs
    // ---- issue 16 A-loads back-to-back (256 B/lane in flight) ----
    const float* Xc = X + ((size_t)b * LL + l0 + arow) * DD + c * 256 + acol;
    float4 pa[16];
    #pragma unroll
    for (int i = 0; i < 16; ++i) pa[i] = *(const float4*)(Xc + i * 4);
    // ---- B(c, step 0) ----
    #pragma unroll
    for (int j = 0; j < 4; ++j) {
      int fl = tid + j * 256, m = fl >> 2, ch = fl & 3;
      GLL16(Pb + (size_t)m * DD + c * 256 + (ch ^ keyf(m)) * 8, &Bs[0][fl * 8]);
    }
    // ---- cvt + swizzled LDS write ----
    #pragma unroll
    for (int i = 0; i < 8; ++i) {
      u32x4 v;
      v[0] = cvt2(pa[2 * i].x, pa[2 * i].y);
      v[1] = cvt2(pa[2 * i].z, pa[2 * i].w);
      v[2] = cvt2(pa[2 * i + 1].x, pa[2 * i + 1].y);
      v[3] = cvt2(pa[2 * i + 1].z, pa[2 * i + 1].w);
      int colb = (tid & 3) * 128 + i * 16;
      *(u32x4*)(Asb + (colb ^ akey)) = v;
    }
    __syncthreads();                              // A chunk + B(c,0) ready
    // ---- 8 inner BK=32 steps over resident A chunk ----
    for (int s = 0; s < 8; ++s) {
      int buf = s & 1;
      if (s < 7) {
        #pragma unroll
        for (int j = 0; j < 4; ++j) {
          int fl = tid + j * 256, m = fl >> 2, ch = fl & 3;
          GLL16(Pb + (size_t)m * DD + c * 256 + (s + 1) * 32 + (ch ^ keyf(m)) * 8, &Bs[buf ^ 1][fl * 8]);
        }
      }
      s16x8 af[4], bf[4];
      int colb = s * 64 + kg * 16;
      #pragma unroll
      for (int mi = 0; mi < 4; ++mi) {
        int row = mi * 16 + m16;
        af[mi] = *(const s16x8*)((const char*)As + row * 512 + (colb ^ ((row & 7) << 4)));
      }
      #pragma unroll
      for (int ni = 0; ni < 4; ++ni) {
        int m = w * 64 + ni * 16 + m16;
        bf[ni] = *(const s16x8*)&Bs[buf][m * 32 + (kg ^ keyf(m)) * 8];
      }
      #pragma unroll
      for (int mi = 0; mi < 4; ++mi)
        #pragma unroll
        for (int ni = 0; ni < 4; ++ni)
          acc[mi][ni] = __builtin_amdgcn_mfma_f32_16x16x32_bf16(af[mi], bf[ni], acc[mi][ni], 0, 0, 0);
      if (s < 7) __syncthreads();
    }
  }

  if (mode == 0) {
    #pragma unroll
    for (int mi = 0; mi < 4; ++mi)
      #pragma unroll
      for (int ni = 0; ni < 4; ++ni) {
        int r0 = mi * 16 + (kg << 2);
        int c = w * 64 + ni * 16 + m16;
        #pragma unroll
        for (int u = 0; u < 4; ++u)
          rfq[((size_t)b * LL + l0 + r0 + u) * MM + c] = f2b(expf(acc[mi][ni][u] * 0.03125f) * 0.0625f);
      }
  } else {
    // bounce C^T into Bs overlay [256 m][64 l] (32 KB), fused Z partials
    __syncthreads();                              // all compute reads of Bs done
    short* T = (short*)Bs;
    float zp[4] = {0.f, 0.f, 0.f, 0.f};
    #pragma unroll
    for (int mi = 0; mi < 4; ++mi)
      #pragma unroll
      for (int ni = 0; ni < 4; ++ni) {
        int l = mi * 16 + (kg << 2);
        int m = w * 64 + ni * 16 + m16;
        int key = (m & 7) << 3;
        float e0 = expf(acc[mi][ni][0] * 0.03125f);
        float e1 = expf(acc[mi][ni][1] * 0.03125f);
        float e2 = expf(acc[mi][ni][2] * 0.03125f);
        float e3 = expf(acc[mi][ni][3] * 0.03125f);
        zp[ni] += e0 + e1 + e2 + e3;
        *(unsigned*)&T[m * 64 + (l ^ key)] = cvt2(e0, e1);
        *(unsigned*)&T[m * 64 + ((l ^ key) + 2)] = cvt2(e2, e3);
      }
    #pragma unroll
    for (int ni = 0; ni < 4; ++ni) {
      zp[ni] += __shfl_xor(zp[ni], 16);
      zp[ni] += __shfl_xor(zp[ni], 32);
    }
    if (kg == 0) {
      #pragma unroll
      for (int ni = 0; ni < 4; ++ni)
        atomicAdd(&Zz[b * MM + w * 64 + ni * 16 + m16], zp[ni]);
    }
    __syncthreads();
    int m = tid, mkey = (m & 7) << 3;
    short* dst = rfkT + ((size_t)b * MM + m) * LL + l0;
    #pragma unroll
    for (int j = 0; j < 8; ++j) {
      s16x8 v = *(const s16x8*)&T[m * 64 + ((j * 8) ^ mkey)];
      *(s16x8*)(dst + j * 8) = v;
    }
  }
}

// ---------------- KV partials: KVp[kc][b][d][m] = sum over 512 l; NO atomics ----------------
__global__ __launch_bounds__(512) void k_kv(const float* __restrict__ V, const short* __restrict__ rfkT,
                                            float* __restrict__ KVp) {
  __shared__ float Vs[2][32 * 129];   // fp32 [32 l][129 d-pitch] (odd pitch: conflict-free col reads)
  __shared__ short Ak[2][256 * 32];   // rfkT [256 m][32 l] bf16, 4-chunk swizzled
  int d0 = blockIdx.x * 128, kc = blockIdx.y, b = blockIdx.z;
  int ls = kc * 512;
  int tid = threadIdx.x, lane = tid & 63, w = tid >> 6;
  int wm = w >> 1, wd = w & 1;     // 4(m) x 2(d)
  int m16 = lane & 15, kg = lane >> 4;

  int vl = tid >> 4, vf = (tid & 15) * 8;
  const float* Vb = V + ((size_t)b * LL + ls + vl) * DD + d0 + vf;

  int am = tid >> 2, as = tid & 3;
  int acs = as ^ keyf(am);
  const short* AkS0 = rfkT + ((size_t)b * MM + am) * LL + ls + acs * 8;
  const short* AkS1 = rfkT + ((size_t)b * MM + am + 128) * LL + ls + acs * 8;

  fx4 acc[4][4] = {};
  float4 pv0, pv1;

  pv0 = *(const float4*)(Vb);
  pv1 = *(const float4*)(Vb + 4);
  GLL16(AkS0, &Ak[0][tid * 8]);
  GLL16(AkS1, &Ak[0][(tid + 512) * 8]);
  #pragma unroll
  for (int j = 0; j < 4; ++j) {
    Vs[0][vl * 129 + vf + j] = ((const float*)&pv0)[j];
    Vs[0][vl * 129 + vf + 4 + j] = ((const float*)&pv1)[j];
  }
  __syncthreads();

  for (int ch = 0; ch < 16; ++ch) {
    int cur = ch & 1, nxt = cur ^ 1;
    if (ch < 15) {
      int lo = (ch + 1) * 32;
      pv0 = *(const float4*)(Vb + (size_t)lo * DD);
      pv1 = *(const float4*)(Vb + (size_t)lo * DD + 4);
      GLL16(AkS0 + lo, &Ak[nxt][tid * 8]);
      GLL16(AkS1 + lo, &Ak[nxt][(tid + 512) * 8]);
    }
    s16x8 af[4];
    #pragma unroll
    for (int mi = 0; mi < 4; ++mi) {
      int m = wm * 64 + mi * 16 + m16;
      af[mi] = *(const s16x8*)&Ak[cur][m * 32 + ((kg ^ keyf(m)) * 8)];
    }
    #pragma unroll
    for (int ni = 0; ni < 4; ++ni) {
      int d = wd * 64 + ni * 16 + m16;
      const float* vs = &Vs[cur][kg * 8 * 129 + d];
      u32x4 bw;
      bw[0] = cvt2(vs[0], vs[129]);
      bw[1] = cvt2(vs[258], vs[387]);
      bw[2] = cvt2(vs[516], vs[645]);
      bw[3] = cvt2(vs[774], vs[903]);
      s16x8 bf = *(s16x8*)&bw;
      #pragma unroll
      for (int mi = 0; mi < 4; ++mi)
        acc[mi][ni] = __builtin_amdgcn_mfma_f32_16x16x32_bf16(af[mi], bf, acc[mi][ni], 0, 0, 0);
    }
    if (ch < 15) {
      #pragma unroll
      for (int j = 0; j < 4; ++j) {
        Vs[nxt][vl * 129 + vf + j] = ((const float*)&pv0)[j];
        Vs[nxt][vl * 129 + vf + 4 + j] = ((const float*)&pv1)[j];
      }
    }
    __syncthreads();
  }

  float* dst = KVp + (((size_t)kc * NB + b) * DD + d0) * MM;
  #pragma unroll
  for (int mi = 0; mi < 4; ++mi)
    #pragma unroll
    for (int ni = 0; ni < 4; ++ni) {
      int d = wd * 64 + ni * 16 + m16;
      int m = wm * 64 + mi * 16 + (kg << 2);
      *(float4*)(dst + (size_t)d * MM + m) = *(float4*)&acc[mi][ni];
    }
}

// ---------------- reduce 8 split-K partials -> KVTf fp32 ----------------
__global__ __launch_bounds__(256) void k_red(const float* __restrict__ KVp, float* __restrict__ KVTf) {
  int i = blockIdx.x * 256 + threadIdx.x;
  const float4* p = (const float4*)KVp;
  float4 s = p[i];
  #pragma unroll
  for (int k = 1; k < 8; ++k) {
    float4 v = p[i + k * 262144];
    s.x += v.x; s.y += v.y; s.z += v.z; s.w += v.w;
  }
  ((float4*)KVTf)[i] = s;
}

// ---------------- out = (rf_q x KVT^T) / (rf_q . Z + eps); KVTf read fp32 ----------------
__global__ __launch_bounds__(512) void k_out(const short* __restrict__ rfq, const float* __restrict__ KVTf,
                                             const float* __restrict__ Zz, float* __restrict__ out) {
  __shared__ short Aq[2][8192];   // [128 l][64 m]
  __shared__ short Bv[2][8192];   // [128 d][64 m]
  __shared__ float zl[256];
  __shared__ float np[512];
  __shared__ float nf[128];
  int l0 = blockIdx.x * 128, d0 = blockIdx.y * 128, b = blockIdx.z;
  int tid = threadIdx.x, lane = tid & 63, w = tid >> 6;
  int wr = w >> 2, wc = w & 3;               // 2(l) x 4(d)
  int brow = tid >> 2, bq = (tid & 3) * 16;
  int bkey = (brow & 7) << 3;
  const float* Kf = KVTf + ((size_t)b * DD + d0 + brow) * MM + bq;
  short* Bw0 = &Bv[0][brow * 64 + (bq ^ bkey)];
  short* Bw1 = &Bv[0][brow * 64 + ((bq + 8) ^ bkey)];
  const short* Ab = rfq + ((size_t)b * LL + l0) * MM;
  int f1 = tid + 512;
  int ar0 = tid >> 3, ac0 = tid & 7, ar1 = f1 >> 3, ac1 = f1 & 7;
  int nrow = tid & 127, nsub = tid >> 7;
  if (tid < 256) zl[tid] = Zz[b * MM + tid];
  fx4 acc[4][2] = {};
  float4 pb[4];
  float na = 0.f;

  #pragma unroll
  for (int i = 0; i < 4; ++i) pb[i] = *(const float4*)(Kf + i * 4);
  GLL16(Ab + (size_t)ar0 * MM + (ac0 ^ (ar0 & 7)) * 8, &Aq[0][tid * 8]);
  GLL16(Ab + (size_t)ar1 * MM + (ac1 ^ (ar1 & 7)) * 8, &Aq[0][f1 * 8]);
  {
    u32x2 v0, v1;
    v0[0] = cvt2(pb[0].x, pb[0].y); v0[1] = cvt2(pb[0].z, pb[0].w);
    v1[0] = cvt2(pb[1].x, pb[1].y); v1[1] = cvt2(pb[1].z, pb[1].w);
    *(u32x2*)Bw0 = v0;
    *(u32x2*)(Bw0 + 4) = v1;
    v0[0] = cvt2(pb[2].x, pb[2].y); v0[1] = cvt2(pb[2].z, pb[2].w);
    v1[0] = cvt2(pb[3].x, pb[3].y); v1[1] = cvt2(pb[3].z, pb[3].w);
    *(u32x2*)Bw1 = v0;
    *(u32x2*)(Bw1 + 4) = v1;
  }
  __syncthreads();

  for (int t = 0; t < 4; ++t) {
    int cur = t & 1, nxt = cur ^ 1;
    int m1 = ((t + 1) & 3) * 64;
    #pragma unroll
    for (int i = 0; i < 4; ++i) pb[i] = *(const float4*)(Kf + m1 + i * 4);
    GLL16(Ab + (size_t)ar0 * MM + m1 + (ac0 ^ (ar0 & 7)) * 8, &Aq[nxt][tid * 8]);
    GLL16(Ab + (size_t)ar1 * MM + m1 + (ac1 ^ (ar1 & 7)) * 8, &Aq[nxt][f1 * 8]);
    #pragma unroll
    for (int kk = 0; kk < 16; ++kk) {
      int k = nsub * 16 + kk;
      na += b2f(Aq[cur][nrow * 64 + (k ^ ((nrow & 7) << 3))]) * zl[t * 64 + k];
    }
    #pragma unroll
    for (int ks = 0; ks < 2; ++ks) {
      int kb = ks * 32 + (lane >> 4) * 8;
      s16x8 af[4], bf[2];
      #pragma unroll
      for (int mi = 0; mi < 4; ++mi) {
        int row = wr * 64 + mi * 16 + (lane & 15);
        af[mi] = *(const s16x8*)&Aq[cur][row * 64 + (kb ^ ((row & 7) << 3))];
      }
      #pragma unroll
      for (int ni = 0; ni < 2; ++ni) {
        int row = wc * 32 + ni * 16 + (lane & 15);
        bf[ni] = *(const s16x8*)&Bv[cur][row * 64 + (kb ^ ((row & 7) << 3))];
      }
      #pragma unroll
      for (int mi = 0; mi < 4; ++mi)
        #pragma unroll
        for (int ni = 0; ni < 2; ++ni)
          acc[mi][ni] = __builtin_amdgcn_mfma_f32_16x16x32_bf16(af[mi], bf[ni], acc[mi][ni], 0, 0, 0);
    }
    {
      u32x2 v0, v1;
      v0[0] = cvt2(pb[0].x, pb[0].y); v0[1] = cvt2(pb[0].z, pb[0].w);
      v1[0] = cvt2(pb[1].x, pb[1].y); v1[1] = cvt2(pb[1].z, pb[1].w);
      *(u32x2*)(Bw0 + nxt * 8192) = v0;
      *(u32x2*)(Bw0 + nxt * 8192 + 4) = v1;
      v0[0] = cvt2(pb[2].x, pb[2].y); v0[1] = cvt2(pb[2].z, pb[2].w);
      v1[0] = cvt2(pb[3].x, pb[3].y); v1[1] = cvt2(pb[3].z, pb[3].w);
      *(u32x2*)(Bw1 + nxt * 8192) = v0;
      *(u32x2*)(Bw1 + nxt * 8192 + 4) = v1;
    }
    __syncthreads();
  }
  np[tid] = na;
  __syncthreads();
  if (tid < 128) nf[tid] = np[tid] + np[tid + 128] + np[tid + 256] + np[tid + 384] + 1e-6f;
  __syncthreads();
  #pragma unroll
  for (int mi = 0; mi < 4; ++mi)
    #pragma unroll
    for (int ni = 0; ni < 2; ++ni) {
      int l = wr * 64 + mi * 16 + ((lane >> 4) << 2);
      int d = d0 + wc * 32 + ni * 16 + (lane & 15);
      #pragma unroll
      for (int u = 0; u < 4; ++u)
        out[((size_t)b * LL + l0 + l + u) * DD + d] = acc[mi][ni][u] / nf[l + u];
    }
}

extern "C" void kernel_launch(void* const* d_in, const int* in_sizes, int n_in,
                              void* d_out, int out_size, void* d_ws, size_t ws_size,
                              hipStream_t stream) {
  const float* Q = (const float*)d_in[0];
  const float* K = (const float*)d_in[1];
  const float* V = (const float*)d_in[2];
  const float* P = (const float*)d_in[3];
  float* out = (float*)d_out;
  char* ws = (char*)d_ws;

  short* Pb   = (short*)(ws + 0);          // 256*1024*2    = 512 KB
  float* Zz   = (float*)(ws + 524288);     // 4*256*4       = 4 KB
  float* KVTf = (float*)(ws + 528384);     // 4*1024*256*4  = 4 MB
  short* rfq  = (short*)(ws + 4722688);    // 4*4096*256*2  = 8 MB
  short* rfkT = (short*)(ws + 13111296);   // 4*256*4096*2  = 8 MB
  float* KVp  = (float*)(ws + 21499904);   // 8*4*1024*256*4 = 32 MB

  k_cast<<<256, 256, 0, stream>>>(P, Pb, 65536);
  (void)hipMemsetAsync(Zz, 0, 4096, stream);
  k_qk<<<dim3(64, 1, 2 * NB), 256, 0, stream>>>(Q, K, Pb, rfq, rfkT, Zz);
  k_kv<<<dim3(8, 8, NB), 512, 0, stream>>>(V, rfkT, KVp);
  k_red<<<1024, 256, 0, stream>>>(KVp, KVTf);
  k_out<<<dim3(32, 8, NB), 512, 0, stream>>>(rfq, KVTf, Zz, out);
}

// Round 9
// 141.213 us; speedup vs baseline: 1.0338x; 1.0338x over previous
//
#include <hip/hip_runtime.h>
#include <math.h>

#define NB 4
#define LL 4096
#define DD 1024
#define MM 256

typedef short s16x8 __attribute__((ext_vector_type(8)));
typedef short s16x4 __attribute__((ext_vector_type(4)));
typedef float fx4 __attribute__((ext_vector_type(4)));
typedef unsigned u32x2 __attribute__((ext_vector_type(2)));
typedef unsigned u32x4 __attribute__((ext_vector_type(4)));

__device__ __forceinline__ float b2f(short s) {
  union { unsigned u; float f; } v;
  v.u = ((unsigned)(unsigned short)s) << 16;
  return v.f;
}
__device__ __forceinline__ short f2b(float f) {
  union { float f; unsigned u; } v;
  v.f = f;
  unsigned r = (v.u + 0x7fffu + ((v.u >> 16) & 1u)) >> 16;
  return (short)(unsigned short)r;
}
// packed fp32->bf16 (RNE), 2 values per instruction
__device__ __forceinline__ unsigned cvt2(float lo, float hi) {
  unsigned r;
  asm("v_cvt_pk_bf16_f32 %0, %1, %2" : "=v"(r) : "v"(lo), "v"(hi));
  return r;
}
// 4-chunk swizzle key for 32-k-wide bf16 tiles
__device__ __forceinline__ int keyf(int m) { return (m ^ (m >> 2)) & 3; }

typedef __attribute__((address_space(1))) const void* gas1_t;
typedef __attribute__((address_space(3))) void* las3_t;
#define GLL16(g, l) __builtin_amdgcn_global_load_lds((gas1_t)(const void*)(g), (las3_t)(void*)(l), 16, 0, 0)

// ---------------- cast fp32 -> bf16 (P only) ----------------
__global__ __launch_bounds__(256) void k_cast(const float* __restrict__ in, short* __restrict__ out, int n4) {
  int i = blockIdx.x * 256 + threadIdx.x;
  if (i >= n4) return;
  float4 v = ((const float4*)in)[i];
  s16x4 s;
  s[0] = f2b(v.x); s[1] = f2b(v.y); s[2] = f2b(v.z); s[3] = f2b(v.w);
  ((s16x4*)out)[i] = s;
}

// ---------------- rf GEMM: 64l x 256m, BK=32, all-GLL16, counted-vmcnt 2-barrier pipeline ----------------
// A staged fp32 (cvt at fragment build); B bf16. 6 GLL16/thread/step exactly -> vmcnt(6).
// z<4: rf_q (B,L,M) incl 1/sqrt(M); z>=4: rf_kT (B,M,L) + Z atomics.
__global__ __launch_bounds__(256, 2) void k_qk(const float* __restrict__ Q, const float* __restrict__ K,
                                               const short* __restrict__ Pb,
                                               short* __restrict__ rfq, short* __restrict__ rfkT,
                                               float* __restrict__ Zz) {
  __shared__ float As[2][2048];   // [64 l][32 k] fp32, 16B-granule XOR-swz, 8KB x2
  __shared__ short Bs[2][8192];   // [256 m][32 k] bf16, keyf chunk swz, 16KB x2
  int z = blockIdx.z, mode = z >> 2, b = z & 3;
  int l0 = blockIdx.x * 64;
  const float* X = mode ? K : Q;
  int tid = threadIdx.x, lane = tid & 63, w = tid >> 6;   // wave grid 1(l) x 4(m)
  int m16 = lane & 15, kg = lane >> 4;

  // precomputed staging sources (k-offset added per step)
  int af0 = tid, af1 = tid + 256;
  int ar0 = af0 >> 3, ag0 = af0 & 7, ar1 = af1 >> 3, ag1 = af1 & 7;
  const float* aS0 = X + ((size_t)b * LL + l0 + ar0) * DD + (ag0 ^ (ar0 & 7)) * 4;
  const float* aS1 = X + ((size_t)b * LL + l0 + ar1) * DD + (ag1 ^ (ar1 & 7)) * 4;
  const short* bS[4];
  #pragma unroll
  for (int j = 0; j < 4; ++j) {
    int fl = tid + j * 256, m = fl >> 2, ch = fl & 3;
    bS[j] = Pb + (size_t)m * DD + (ch ^ keyf(m)) * 8;
  }

  fx4 acc[4][4] = {};

  // prologue: stage tile 0 into buf 0
  {
    GLL16(aS0, &As[0][af0 * 4]);
    GLL16(aS1, &As[0][af1 * 4]);
    #pragma unroll
    for (int j = 0; j < 4; ++j) GLL16(bS[j], &Bs[0][(tid + j * 256) * 8]);
  }

  for (int t = 0; t < 32; ++t) {
    int cur = t & 1, nxt = cur ^ 1;
    if (t < 31) {
      int ko = (t + 1) * 32;
      GLL16(aS0 + ko, &As[nxt][af0 * 4]);
      GLL16(aS1 + ko, &As[nxt][af1 * 4]);
      #pragma unroll
      for (int j = 0; j < 4; ++j) GLL16(bS[j] + ko, &Bs[nxt][(tid + j * 256) * 8]);
    }
    __builtin_amdgcn_sched_barrier(0);
    if (t < 31) asm volatile("s_waitcnt vmcnt(6)" ::: "memory");
    else        asm volatile("s_waitcnt vmcnt(0)" ::: "memory");
    __builtin_amdgcn_sched_barrier(0);
    __builtin_amdgcn_s_barrier();         // tile t ready for all waves
    __builtin_amdgcn_sched_barrier(0);

    s16x8 af[4], bf[4];
    #pragma unroll
    for (int mi = 0; mi < 4; ++mi) {
      int r = mi * 16 + m16, rk = r & 7;
      const float* pr = &As[cur][r * 32];
      fx4 a0 = *(const fx4*)(pr + ((2 * kg) ^ rk) * 4);
      fx4 a1 = *(const fx4*)(pr + ((2 * kg + 1) ^ rk) * 4);
      u32x4 aw;
      aw[0] = cvt2(a0[0], a0[1]); aw[1] = cvt2(a0[2], a0[3]);
      aw[2] = cvt2(a1[0], a1[1]); aw[3] = cvt2(a1[2], a1[3]);
      af[mi] = *(s16x8*)&aw;
    }
    #pragma unroll
    for (int ni = 0; ni < 4; ++ni) {
      int m = w * 64 + ni * 16 + m16;
      bf[ni] = *(const s16x8*)&Bs[cur][m * 32 + (kg ^ keyf(m)) * 8];
    }
    #pragma unroll
    for (int mi = 0; mi < 4; ++mi)
      #pragma unroll
      for (int ni = 0; ni < 4; ++ni)
        acc[mi][ni] = __builtin_amdgcn_mfma_f32_16x16x32_bf16(af[mi], bf[ni], acc[mi][ni], 0, 0, 0);

    __builtin_amdgcn_sched_barrier(0);
    __builtin_amdgcn_s_barrier();         // all waves done reading buf cur
    __builtin_amdgcn_sched_barrier(0);
  }

  if (mode == 0) {
    #pragma unroll
    for (int mi = 0; mi < 4; ++mi)
      #pragma unroll
      for (int ni = 0; ni < 4; ++ni) {
        int r0 = mi * 16 + (kg << 2);
        int c = w * 64 + ni * 16 + m16;
        #pragma unroll
        for (int u = 0; u < 4; ++u)
          rfq[((size_t)b * LL + l0 + r0 + u) * MM + c] = f2b(expf(acc[mi][ni][u] * 0.03125f) * 0.0625f);
      }
  } else {
    // bounce C^T into Bs overlay [256 m][64 l] (32 KB), fused Z partials
    __syncthreads();
    short* T = (short*)Bs;
    float zp[4] = {0.f, 0.f, 0.f, 0.f};
    #pragma unroll
    for (int mi = 0; mi < 4; ++mi)
      #pragma unroll
      for (int ni = 0; ni < 4; ++ni) {
        int l = mi * 16 + (kg << 2);
        int m = w * 64 + ni * 16 + m16;
        int key = (m & 7) << 3;
        float e0 = expf(acc[mi][ni][0] * 0.03125f);
        float e1 = expf(acc[mi][ni][1] * 0.03125f);
        float e2 = expf(acc[mi][ni][2] * 0.03125f);
        float e3 = expf(acc[mi][ni][3] * 0.03125f);
        zp[ni] += e0 + e1 + e2 + e3;
        *(unsigned*)&T[m * 64 + (l ^ key)] = cvt2(e0, e1);
        *(unsigned*)&T[m * 64 + ((l ^ key) + 2)] = cvt2(e2, e3);
      }
    #pragma unroll
    for (int ni = 0; ni < 4; ++ni) {
      zp[ni] += __shfl_xor(zp[ni], 16);
      zp[ni] += __shfl_xor(zp[ni], 32);
    }
    if (kg == 0) {
      #pragma unroll
      for (int ni = 0; ni < 4; ++ni)
        atomicAdd(&Zz[b * MM + w * 64 + ni * 16 + m16], zp[ni]);
    }
    __syncthreads();
    int m = tid, mkey = (m & 7) << 3;
    short* dst = rfkT + ((size_t)b * MM + m) * LL + l0;
    #pragma unroll
    for (int j = 0; j < 8; ++j) {
      s16x8 v = *(const s16x8*)&T[m * 64 + ((j * 8) ^ mkey)];
      *(s16x8*)(dst + j * 8) = v;
    }
  }
}

// ---------------- KV partials: KVp[kc][b][d][m] = sum over 512 l; NO atomics ----------------
__global__ __launch_bounds__(512) void k_kv(const float* __restrict__ V, const short* __restrict__ rfkT,
                                            float* __restrict__ KVp) {
  __shared__ float Vs[2][32 * 129];   // fp32 [32 l][129 d-pitch] (odd pitch: conflict-free col reads)
  __shared__ short Ak[2][256 * 32];   // rfkT [256 m][32 l] bf16, 4-chunk swizzled
  int d0 = blockIdx.x * 128, kc = blockIdx.y, b = blockIdx.z;
  int ls = kc * 512;
  int tid = threadIdx.x, lane = tid & 63, w = tid >> 6;
  int wm = w >> 1, wd = w & 1;     // 4(m) x 2(d)
  int m16 = lane & 15, kg = lane >> 4;

  int vl = tid >> 4, vf = (tid & 15) * 8;
  const float* Vb = V + ((size_t)b * LL + ls + vl) * DD + d0 + vf;

  int am = tid >> 2, as = tid & 3;
  int acs = as ^ keyf(am);
  const short* AkS0 = rfkT + ((size_t)b * MM + am) * LL + ls + acs * 8;
  const short* AkS1 = rfkT + ((size_t)b * MM + am + 128) * LL + ls + acs * 8;

  fx4 acc[4][4] = {};
  float4 pv0, pv1;

  pv0 = *(const float4*)(Vb);
  pv1 = *(const float4*)(Vb + 4);
  GLL16(AkS0, &Ak[0][tid * 8]);
  GLL16(AkS1, &Ak[0][(tid + 512) * 8]);
  #pragma unroll
  for (int j = 0; j < 4; ++j) {
    Vs[0][vl * 129 + vf + j] = ((const float*)&pv0)[j];
    Vs[0][vl * 129 + vf + 4 + j] = ((const float*)&pv1)[j];
  }
  __syncthreads();

  for (int ch = 0; ch < 16; ++ch) {
    int cur = ch & 1, nxt = cur ^ 1;
    if (ch < 15) {
      int lo = (ch + 1) * 32;
      pv0 = *(const float4*)(Vb + (size_t)lo * DD);
      pv1 = *(const float4*)(Vb + (size_t)lo * DD + 4);
      GLL16(AkS0 + lo, &Ak[nxt][tid * 8]);
      GLL16(AkS1 + lo, &Ak[nxt][(tid + 512) * 8]);
    }
    s16x8 af[4];
    #pragma unroll
    for (int mi = 0; mi < 4; ++mi) {
      int m = wm * 64 + mi * 16 + m16;
      af[mi] = *(const s16x8*)&Ak[cur][m * 32 + ((kg ^ keyf(m)) * 8)];
    }
    #pragma unroll
    for (int ni = 0; ni < 4; ++ni) {
      int d = wd * 64 + ni * 16 + m16;
      const float* vs = &Vs[cur][kg * 8 * 129 + d];
      u32x4 bw;
      bw[0] = cvt2(vs[0], vs[129]);
      bw[1] = cvt2(vs[258], vs[387]);
      bw[2] = cvt2(vs[516], vs[645]);
      bw[3] = cvt2(vs[774], vs[903]);
      s16x8 bf = *(s16x8*)&bw;
      #pragma unroll
      for (int mi = 0; mi < 4; ++mi)
        acc[mi][ni] = __builtin_amdgcn_mfma_f32_16x16x32_bf16(af[mi], bf, acc[mi][ni], 0, 0, 0);
    }
    if (ch < 15) {
      #pragma unroll
      for (int j = 0; j < 4; ++j) {
        Vs[nxt][vl * 129 + vf + j] = ((const float*)&pv0)[j];
        Vs[nxt][vl * 129 + vf + 4 + j] = ((const float*)&pv1)[j];
      }
    }
    __syncthreads();
  }

  float* dst = KVp + (((size_t)kc * NB + b) * DD + d0) * MM;
  #pragma unroll
  for (int mi = 0; mi < 4; ++mi)
    #pragma unroll
    for (int ni = 0; ni < 4; ++ni) {
      int d = wd * 64 + ni * 16 + m16;
      int m = wm * 64 + mi * 16 + (kg << 2);
      *(float4*)(dst + (size_t)d * MM + m) = *(float4*)&acc[mi][ni];
    }
}

// ---------------- reduce 8 split-K partials -> KVTf fp32 ----------------
__global__ __launch_bounds__(256) void k_red(const float* __restrict__ KVp, float* __restrict__ KVTf) {
  int i = blockIdx.x * 256 + threadIdx.x;
  const float4* p = (const float4*)KVp;
  float4 s = p[i];
  #pragma unroll
  for (int k = 1; k < 8; ++k) {
    float4 v = p[i + k * 262144];
    s.x += v.x; s.y += v.y; s.z += v.z; s.w += v.w;
  }
  ((float4*)KVTf)[i] = s;
}

// ---------------- out = (rf_q x KVT^T) / (rf_q . Z + eps); KVTf read fp32 ----------------
__global__ __launch_bounds__(512) void k_out(const short* __restrict__ rfq, const float* __restrict__ KVTf,
                                             const float* __restrict__ Zz, float* __restrict__ out) {
  __shared__ short Aq[2][8192];   // [128 l][64 m]
  __shared__ short Bv[2][8192];   // [128 d][64 m]
  __shared__ float zl[256];
  __shared__ float np[512];
  __shared__ float nf[128];
  int l0 = blockIdx.x * 128, d0 = blockIdx.y * 128, b = blockIdx.z;
  int tid = threadIdx.x, lane = tid & 63, w = tid >> 6;
  int wr = w >> 2, wc = w & 3;               // 2(l) x 4(d)
  int brow = tid >> 2, bq = (tid & 3) * 16;
  int bkey = (brow & 7) << 3;
  const float* Kf = KVTf + ((size_t)b * DD + d0 + brow) * MM + bq;
  short* Bw0 = &Bv[0][brow * 64 + (bq ^ bkey)];
  short* Bw1 = &Bv[0][brow * 64 + ((bq + 8) ^ bkey)];
  const short* Ab = rfq + ((size_t)b * LL + l0) * MM;
  int f1 = tid + 512;
  int ar0 = tid >> 3, ac0 = tid & 7, ar1 = f1 >> 3, ac1 = f1 & 7;
  int nrow = tid & 127, nsub = tid >> 7;
  if (tid < 256) zl[tid] = Zz[b * MM + tid];
  fx4 acc[4][2] = {};
  float4 pb[4];
  float na = 0.f;

  #pragma unroll
  for (int i = 0; i < 4; ++i) pb[i] = *(const float4*)(Kf + i * 4);
  GLL16(Ab + (size_t)ar0 * MM + (ac0 ^ (ar0 & 7)) * 8, &Aq[0][tid * 8]);
  GLL16(Ab + (size_t)ar1 * MM + (ac1 ^ (ar1 & 7)) * 8, &Aq[0][f1 * 8]);
  {
    u32x2 v0, v1;
    v0[0] = cvt2(pb[0].x, pb[0].y); v0[1] = cvt2(pb[0].z, pb[0].w);
    v1[0] = cvt2(pb[1].x, pb[1].y); v1[1] = cvt2(pb[1].z, pb[1].w);
    *(u32x2*)Bw0 = v0;
    *(u32x2*)(Bw0 + 4) = v1;
    v0[0] = cvt2(pb[2].x, pb[2].y); v0[1] = cvt2(pb[2].z, pb[2].w);
    v1[0] = cvt2(pb[3].x, pb[3].y); v1[1] = cvt2(pb[3].z, pb[3].w);
    *(u32x2*)Bw1 = v0;
    *(u32x2*)(Bw1 + 4) = v1;
  }
  __syncthreads();

  for (int t = 0; t < 4; ++t) {
    int cur = t & 1, nxt = cur ^ 1;
    int m1 = ((t + 1) & 3) * 64;
    #pragma unroll
    for (int i = 0; i < 4; ++i) pb[i] = *(const float4*)(Kf + m1 + i * 4);
    GLL16(Ab + (size_t)ar0 * MM + m1 + (ac0 ^ (ar0 & 7)) * 8, &Aq[nxt][tid * 8]);
    GLL16(Ab + (size_t)ar1 * MM + m1 + (ac1 ^ (ar1 & 7)) * 8, &Aq[nxt][f1 * 8]);
    #pragma unroll
    for (int kk = 0; kk < 16; ++kk) {
      int k = nsub * 16 + kk;
      na += b2f(Aq[cur][nrow * 64 + (k ^ ((nrow & 7) << 3))]) * zl[t * 64 + k];
    }
    #pragma unroll
    for (int ks = 0; ks < 2; ++ks) {
      int kb = ks * 32 + (lane >> 4) * 8;
      s16x8 af[4], bf[2];
      #pragma unroll
      for (int mi = 0; mi < 4; ++mi) {
        int row = wr * 64 + mi * 16 + (lane & 15);
        af[mi] = *(const s16x8*)&Aq[cur][row * 64 + (kb ^ ((row & 7) << 3))];
      }
      #pragma unroll
      for (int ni = 0; ni < 2; ++ni) {
        int row = wc * 32 + ni * 16 + (lane & 15);
        bf[ni] = *(const s16x8*)&Bv[cur][row * 64 + (kb ^ ((row & 7) << 3))];
      }
      #pragma unroll
      for (int mi = 0; mi < 4; ++mi)
        #pragma unroll
        for (int ni = 0; ni < 2; ++ni)
          acc[mi][ni] = __builtin_amdgcn_mfma_f32_16x16x32_bf16(af[mi], bf[ni], acc[mi][ni], 0, 0, 0);
    }
    {
      u32x2 v0, v1;
      v0[0] = cvt2(pb[0].x, pb[0].y); v0[1] = cvt2(pb[0].z, pb[0].w);
      v1[0] = cvt2(pb[1].x, pb[1].y); v1[1] = cvt2(pb[1].z, pb[1].w);
      *(u32x2*)(Bw0 + nxt * 8192) = v0;
      *(u32x2*)(Bw0 + nxt * 8192 + 4) = v1;
      v0[0] = cvt2(pb[2].x, pb[2].y); v0[1] = cvt2(pb[2].z, pb[2].w);
      v1[0] = cvt2(pb[3].x, pb[3].y); v1[1] = cvt2(pb[3].z, pb[3].w);
      *(u32x2*)(Bw1 + nxt * 8192) = v0;
      *(u32x2*)(Bw1 + nxt * 8192 + 4) = v1;
    }
    __syncthreads();
  }
  np[tid] = na;
  __syncthreads();
  if (tid < 128) nf[tid] = np[tid] + np[tid + 128] + np[tid + 256] + np[tid + 384] + 1e-6f;
  __syncthreads();
  #pragma unroll
  for (int mi = 0; mi < 4; ++mi)
    #pragma unroll
    for (int ni = 0; ni < 2; ++ni) {
      int l = wr * 64 + mi * 16 + ((lane >> 4) << 2);
      int d = d0 + wc * 32 + ni * 16 + (lane & 15);
      #pragma unroll
      for (int u = 0; u < 4; ++u)
        out[((size_t)b * LL + l0 + l + u) * DD + d] = acc[mi][ni][u] / nf[l + u];
    }
}

extern "C" void kernel_launch(void* const* d_in, const int* in_sizes, int n_in,
                              void* d_out, int out_size, void* d_ws, size_t ws_size,
                              hipStream_t stream) {
  const float* Q = (const float*)d_in[0];
  const float* K = (const float*)d_in[1];
  const float* V = (const float*)d_in[2];
  const float* P = (const float*)d_in[3];
  float* out = (float*)d_out;
  char* ws = (char*)d_ws;

  short* Pb   = (short*)(ws + 0);          // 256*1024*2    = 512 KB
  float* Zz   = (float*)(ws + 524288);     // 4*256*4       = 4 KB
  float* KVTf = (float*)(ws + 528384);     // 4*1024*256*4  = 4 MB
  short* rfq  = (short*)(ws + 4722688);    // 4*4096*256*2  = 8 MB
  short* rfkT = (short*)(ws + 13111296);   // 4*256*4096*2  = 8 MB
  float* KVp  = (float*)(ws + 21499904);   // 8*4*1024*256*4 = 32 MB

  k_cast<<<256, 256, 0, stream>>>(P, Pb, 65536);
  (void)hipMemsetAsync(Zz, 0, 4096, stream);
  k_qk<<<dim3(64, 1, 2 * NB), 256, 0, stream>>>(Q, K, Pb, rfq, rfkT, Zz);
  k_kv<<<dim3(8, 8, NB), 512, 0, stream>>>(V, rfkT, KVp);
  k_red<<<1024, 256, 0, stream>>>(KVp, KVTf);
  k_out<<<dim3(32, 8, NB), 512, 0, stream>>>(rfq, KVTf, Zz, out);
}